// Round 1
// baseline (87.767 us; speedup 1.0000x reference)
//
#include <hip/hip_runtime.h>
#include <math.h>

// out[b,i,j,o] = lrelu( sum_k pe[d_k(b,i,j)] @ W[k*H:(k+1)*H, o] + b[o] )
// Factorization: Y[k][r][o] = sum_h pe[r,h]*W[k*H+h, o]  (+ bias folded into k==0)
// then out = lrelu(Y0[rss] + Y1[rse] + Y2[res] + Y3[ree]) elementwise gather-add.

__device__ __forceinline__ float lrelu(float x) {
    return x >= 0.f ? x : 0.01f * x;
}

// ---------------- Kernel 1: Y precompute (tiny GEMM, 537 MFLOP) ----------------
// grid.x = 4 * ceil(NPE/16); block = H (=256) threads, thread = output column o.
// Each block computes a 16-row x H tile of Y_k.
__global__ void precompute_Y(const float* __restrict__ pe,
                             const float* __restrict__ W,
                             const float* __restrict__ bias,
                             float* __restrict__ Y,
                             int NPE, int H) {
    const int ntile = (NPE + 15) / 16;
    const int k  = blockIdx.x / ntile;
    const int r0 = (blockIdx.x % ntile) * 16;
    const int o  = threadIdx.x;

    __shared__ float lds[16][16];

    float acc[16];
#pragma unroll
    for (int t = 0; t < 16; ++t) acc[t] = 0.f;

    for (int h0 = 0; h0 < H; h0 += 16) {
        // stage pe[r0..r0+15][h0..h0+15] (256 threads -> 256 elems)
        {
            int t  = threadIdx.x;
            int rr = r0 + (t >> 4);
            int hh = h0 + (t & 15);
            lds[t >> 4][t & 15] = (rr < NPE) ? pe[rr * H + hh] : 0.f;
        }
        __syncthreads();
#pragma unroll
        for (int hc = 0; hc < 4; ++hc) {
            // 4 coalesced W loads (columns o, rows h0+hc*4 .. +3)
            const float w0 = W[(k * H + h0 + hc * 4 + 0) * H + o];
            const float w1 = W[(k * H + h0 + hc * 4 + 1) * H + o];
            const float w2 = W[(k * H + h0 + hc * 4 + 2) * H + o];
            const float w3 = W[(k * H + h0 + hc * 4 + 3) * H + o];
#pragma unroll
            for (int t2 = 0; t2 < 16; ++t2) {
                // broadcast ds_read_b128 (uniform address -> conflict-free)
                float4 lv = *reinterpret_cast<const float4*>(&lds[t2][hc * 4]);
                acc[t2] += lv.x * w0 + lv.y * w1 + lv.z * w2 + lv.w * w3;
            }
        }
        __syncthreads();
    }

    const float bv = (k == 0) ? bias[o] : 0.f;
#pragma unroll
    for (int t2 = 0; t2 < 16; ++t2) {
        int r = r0 + t2;
        if (r < NPE) Y[((size_t)k * NPE + r) * H + o] = acc[t2] + bv;
    }
}

// ---------------- Kernel 2: gather-add + leaky ReLU (write-bound) ----------------
// block = 256 threads handles (b, i, j0..j0+3); thread t: j = j0 + t/64,
// float4 lane o4 = t%64 (H=256 -> 64 float4 per row).
__global__ void gather_add(const int* __restrict__ pos_s,
                           const int* __restrict__ pos_e,
                           const float* __restrict__ Y,
                           float* __restrict__ out,
                           int B, int S, int H, int ML, int NPE) {
    const int SJ  = S >> 2;              // j-tiles per row
    const int blk = blockIdx.x;
    const int jt  = blk % SJ;
    const int rem = blk / SJ;
    const int i   = rem % S;
    const int bb  = rem / S;

    const int t  = threadIdx.x;
    const int j  = (jt << 2) + (t >> 6);
    const int o4 = t & 63;

    const int si = pos_s[bb * S + i];
    const int ei = pos_e[bb * S + i];
    const int sj = pos_s[bb * S + j];
    const int ej = pos_e[bb * S + j];

    const int rss = si - sj + ML;
    const int rse = si - ej + ML;
    const int res = ei - sj + ML;
    const int ree = ei - ej + ML;

    const int HV = H >> 2;
    const float4* __restrict__ Yv = reinterpret_cast<const float4*>(Y);

    float4 a0 = Yv[((size_t)0 * NPE + rss) * HV + o4];
    float4 a1 = Yv[((size_t)1 * NPE + rse) * HV + o4];
    float4 a2 = Yv[((size_t)2 * NPE + res) * HV + o4];
    float4 a3 = Yv[((size_t)3 * NPE + ree) * HV + o4];

    float4 r;
    r.x = lrelu(a0.x + a1.x + a2.x + a3.x);
    r.y = lrelu(a0.y + a1.y + a2.y + a3.y);
    r.z = lrelu(a0.z + a1.z + a2.z + a3.z);
    r.w = lrelu(a0.w + a1.w + a2.w + a3.w);

    reinterpret_cast<float4*>(out)[(((size_t)bb * S + i) * S + j) * HV + o4] = r;
}

// ---------------- Fallback: direct compute (only if ws too small) ----------------
__global__ void direct_kernel(const int* __restrict__ pos_s,
                              const int* __restrict__ pos_e,
                              const float* __restrict__ pe,
                              const float* __restrict__ W,
                              const float* __restrict__ bias,
                              float* __restrict__ out,
                              int B, int S, int H, int ML) {
    const int blk = blockIdx.x;
    const int j   = blk % S;
    const int i   = (blk / S) % S;
    const int bb  = blk / (S * S);
    const int o   = threadIdx.x;

    const int si = pos_s[bb * S + i];
    const int ei = pos_e[bb * S + i];
    const int sj = pos_s[bb * S + j];
    const int ej = pos_e[bb * S + j];

    const int rss = si - sj + ML;
    const int rse = si - ej + ML;
    const int res = ei - sj + ML;
    const int ree = ei - ej + ML;

    float acc = bias[o];
    for (int h = 0; h < H; ++h) {
        acc += pe[rss * H + h] * W[(0 * H + h) * H + o];
        acc += pe[rse * H + h] * W[(1 * H + h) * H + o];
        acc += pe[res * H + h] * W[(2 * H + h) * H + o];
        acc += pe[ree * H + h] * W[(3 * H + h) * H + o];
    }
    out[(((size_t)bb * S + i) * S + j) * H + o] = lrelu(acc);
}

extern "C" void kernel_launch(void* const* d_in, const int* in_sizes, int n_in,
                              void* d_out, int out_size, void* d_ws, size_t ws_size,
                              hipStream_t stream) {
    const int*   pos_s = (const int*)d_in[0];
    const int*   pos_e = (const int*)d_in[1];
    const float* pe    = (const float*)d_in[2];
    const float* W     = (const float*)d_in[3];
    const float* bias  = (const float*)d_in[4];
    float*       out   = (float*)d_out;

    const int H   = in_sizes[4];                 // 256
    const int NPE = in_sizes[2] / H;             // 1025
    const int ML  = (NPE - 1) / 2;               // 512
    const int BS  = in_sizes[0];                 // B*S
    const int S   = (int)((long long)out_size / ((long long)BS * H)); // 256
    const int B   = BS / S;                      // 2

    const size_t need = (size_t)4 * NPE * H * sizeof(float);  // 4.2 MB

    if (ws_size >= need && H == 256 && (S & 3) == 0) {
        float* Y = (float*)d_ws;
        const int ntile = (NPE + 15) / 16;
        precompute_Y<<<4 * ntile, H, 0, stream>>>(pe, W, bias, Y, NPE, H);
        const int nblk = B * S * (S >> 2);
        gather_add<<<nblk, 256, 0, stream>>>(pos_s, pos_e, Y, out, B, S, H, ML, NPE);
    } else {
        direct_kernel<<<B * S * S, H, 0, stream>>>(pos_s, pos_e, pe, W, bias, out,
                                                   B, S, H, ML);
    }
}

// Round 3
// 68.976 us; speedup vs baseline: 1.2724x; 1.2724x over previous
//
#include <hip/hip_runtime.h>
#include <hip/hip_bf16.h>
#include <math.h>

// out[b,i,j,o] = lrelu( sum_k pe[d_k(b,i,j)] @ W[k*H:(k+1)*H, o] + b[o] )
// Factorization: Y[k][r][o] = sum_h pe[r,h]*W[k*H+h, o]  (+ bias folded into k==0),
// Y stored in bf16 (2.1 MB -> fits each XCD's 4 MiB L2), then
// out = lrelu(Y0[rss] + Y1[rse] + Y2[res] + Y3[ree]) as an elementwise gather-add
// with fp32 accumulation and nontemporal fp32 stores.

typedef float f32x4 __attribute__((ext_vector_type(4)));

__device__ __forceinline__ float lrelu(float x) {
    return x >= 0.f ? x : 0.01f * x;
}

__device__ __forceinline__ float bf2f(unsigned short u) {
    union { unsigned int i; float f; } c;
    c.i = ((unsigned int)u) << 16;
    return c.f;
}

// ---------------- Kernel 1: Y precompute (tiny GEMM, 537 MFLOP) ----------------
// grid.x = 4 * ceil(NPE/16); block = H (=256) threads, thread = output column o.
// Each block computes a 16-row x H tile of Y_k, written as bf16.
__global__ void precompute_Y(const float* __restrict__ pe,
                             const float* __restrict__ W,
                             const float* __restrict__ bias,
                             __hip_bfloat16* __restrict__ Y,
                             int NPE, int H) {
    const int ntile = (NPE + 15) / 16;
    const int k  = blockIdx.x / ntile;
    const int r0 = (blockIdx.x % ntile) * 16;
    const int o  = threadIdx.x;

    __shared__ float lds[16][16];

    float acc[16];
#pragma unroll
    for (int t = 0; t < 16; ++t) acc[t] = 0.f;

    for (int h0 = 0; h0 < H; h0 += 16) {
        // stage pe[r0..r0+15][h0..h0+15] (256 threads -> 256 elems)
        {
            int t  = threadIdx.x;
            int rr = r0 + (t >> 4);
            int hh = h0 + (t & 15);
            lds[t >> 4][t & 15] = (rr < NPE) ? pe[rr * H + hh] : 0.f;
        }
        __syncthreads();
#pragma unroll
        for (int hc = 0; hc < 4; ++hc) {
            const float w0 = W[(k * H + h0 + hc * 4 + 0) * H + o];
            const float w1 = W[(k * H + h0 + hc * 4 + 1) * H + o];
            const float w2 = W[(k * H + h0 + hc * 4 + 2) * H + o];
            const float w3 = W[(k * H + h0 + hc * 4 + 3) * H + o];
#pragma unroll
            for (int t2 = 0; t2 < 16; ++t2) {
                float4 lv = *reinterpret_cast<const float4*>(&lds[t2][hc * 4]);
                acc[t2] += lv.x * w0 + lv.y * w1 + lv.z * w2 + lv.w * w3;
            }
        }
        __syncthreads();
    }

    const float bv = (k == 0) ? bias[o] : 0.f;
#pragma unroll
    for (int t2 = 0; t2 < 16; ++t2) {
        int r = r0 + t2;
        if (r < NPE) Y[((size_t)k * NPE + r) * H + o] = __float2bfloat16(acc[t2] + bv);
    }
}

// ---------------- Kernel 2: gather-add + leaky ReLU (write-bound) ----------------
// H = 256 fixed. Block = 256 threads covers one i and 16 j's; 16 lanes per j,
// each thread produces 16 output floats (4 x float4 at columns s*64 + ln*4).
// Table reads: 16 x 8B bf16 loads (L2-resident); stores nontemporal fp32.
__global__ void gather_add_bf16(const int* __restrict__ pos_s,
                                const int* __restrict__ pos_e,
                                const __hip_bfloat16* __restrict__ Y,
                                float* __restrict__ out,
                                int S, int ML, int NPE) {
    const int JT  = 16;
    const int njt = S / JT;
    const int jt  = blockIdx.x % njt;
    const int rem = blockIdx.x / njt;
    const int i   = rem % S;
    const int bb  = rem / S;

    const int t  = threadIdx.x;
    const int j  = jt * JT + (t >> 4);
    const int ln = t & 15;

    const int si = pos_s[bb * S + i];
    const int ei = pos_e[bb * S + i];
    const int sj = pos_s[bb * S + j];
    const int ej = pos_e[bb * S + j];

    const int r0 = si - sj + ML;
    const int r1 = si - ej + ML;
    const int r2 = ei - sj + ML;
    const int r3 = ei - ej + ML;

    const unsigned short* __restrict__ Yu = (const unsigned short*)Y;
    const unsigned short* b0 = Yu + ((size_t)(0 * NPE + r0) << 8) + (ln << 2);
    const unsigned short* b1 = Yu + ((size_t)(1 * NPE + r1) << 8) + (ln << 2);
    const unsigned short* b2 = Yu + ((size_t)(2 * NPE + r2) << 8) + (ln << 2);
    const unsigned short* b3 = Yu + ((size_t)(3 * NPE + r3) << 8) + (ln << 2);

    f32x4* __restrict__ orow =
        reinterpret_cast<f32x4*>(out + ((((size_t)bb * S + i) * S + j) << 8));

#pragma unroll
    for (int s = 0; s < 4; ++s) {
        const int eo = s << 6;  // s*64 element offset
        ushort4 u0 = *reinterpret_cast<const ushort4*>(b0 + eo);
        ushort4 u1 = *reinterpret_cast<const ushort4*>(b1 + eo);
        ushort4 u2 = *reinterpret_cast<const ushort4*>(b2 + eo);
        ushort4 u3 = *reinterpret_cast<const ushort4*>(b3 + eo);

        f32x4 r;
        r.x = lrelu(bf2f(u0.x) + bf2f(u1.x) + bf2f(u2.x) + bf2f(u3.x));
        r.y = lrelu(bf2f(u0.y) + bf2f(u1.y) + bf2f(u2.y) + bf2f(u3.y));
        r.z = lrelu(bf2f(u0.z) + bf2f(u1.z) + bf2f(u2.z) + bf2f(u3.z));
        r.w = lrelu(bf2f(u0.w) + bf2f(u1.w) + bf2f(u2.w) + bf2f(u3.w));

        __builtin_nontemporal_store(r, &orow[(s << 4) + ln]);
    }
}

// ---------------- Fallback: direct compute (only if ws too small) ----------------
__global__ void direct_kernel(const int* __restrict__ pos_s,
                              const int* __restrict__ pos_e,
                              const float* __restrict__ pe,
                              const float* __restrict__ W,
                              const float* __restrict__ bias,
                              float* __restrict__ out,
                              int B, int S, int H, int ML) {
    const int blk = blockIdx.x;
    const int j   = blk % S;
    const int i   = (blk / S) % S;
    const int bb  = blk / (S * S);
    const int o   = threadIdx.x;

    const int si = pos_s[bb * S + i];
    const int ei = pos_e[bb * S + i];
    const int sj = pos_s[bb * S + j];
    const int ej = pos_e[bb * S + j];

    const int rss = si - sj + ML;
    const int rse = si - ej + ML;
    const int res = ei - sj + ML;
    const int ree = ei - ej + ML;

    float acc = bias[o];
    for (int h = 0; h < H; ++h) {
        acc += pe[rss * H + h] * W[(0 * H + h) * H + o];
        acc += pe[rse * H + h] * W[(1 * H + h) * H + o];
        acc += pe[res * H + h] * W[(2 * H + h) * H + o];
        acc += pe[ree * H + h] * W[(3 * H + h) * H + o];
    }
    out[(((size_t)bb * S + i) * S + j) * H + o] = lrelu(acc);
}

extern "C" void kernel_launch(void* const* d_in, const int* in_sizes, int n_in,
                              void* d_out, int out_size, void* d_ws, size_t ws_size,
                              hipStream_t stream) {
    const int*   pos_s = (const int*)d_in[0];
    const int*   pos_e = (const int*)d_in[1];
    const float* pe    = (const float*)d_in[2];
    const float* W     = (const float*)d_in[3];
    const float* bias  = (const float*)d_in[4];
    float*       out   = (float*)d_out;

    const int H   = in_sizes[4];                 // 256
    const int NPE = in_sizes[2] / H;             // 1025
    const int ML  = (NPE - 1) / 2;               // 512
    const int BS  = in_sizes[0];                 // B*S
    const int S   = (int)((long long)out_size / ((long long)BS * H)); // 256
    const int B   = BS / S;                      // 2

    const size_t need = (size_t)4 * NPE * H * sizeof(__hip_bfloat16);  // 2.1 MB

    if (ws_size >= need && H == 256 && (S % 16) == 0) {
        __hip_bfloat16* Y = (__hip_bfloat16*)d_ws;
        const int ntile = (NPE + 15) / 16;
        precompute_Y<<<4 * ntile, H, 0, stream>>>(pe, W, bias, Y, NPE, H);
        const int nblk = B * S * (S / 16);
        gather_add_bf16<<<nblk, 256, 0, stream>>>(pos_s, pos_e, Y, out, S, ML, NPE);
    } else {
        direct_kernel<<<B * S * S, H, 0, stream>>>(pos_s, pos_e, pe, W, bias, out,
                                                   B, S, H, ML);
    }
}

// Round 4
// 52.109 us; speedup vs baseline: 1.6843x; 1.3237x over previous
//
#include <hip/hip_runtime.h>
#include <hip/hip_bf16.h>
#include <math.h>

// out[b,i,j,o] = lrelu( sum_k pe[d_k(b,i,j)] @ W[k*H:(k+1)*H, o] + b[o] )
// Y[k][r][o] = pe[r,:] @ W[k*H:(k+1)*H, o] (+bias in k==0), bf16, 2.1 MB table;
// then out = lrelu(Y0[rss]+Y1[rse]+Y2[res]+Y3[ree]) gather-add, fp32 accum.

typedef float f32x4 __attribute__((ext_vector_type(4)));
typedef float f32x2 __attribute__((ext_vector_type(2)));

__device__ __forceinline__ float lrelu(float x) {
    return fmaxf(x, 0.01f * x);   // works for both signs: max(x, .01x)
}

__device__ __forceinline__ float bf2f(unsigned short u) {
    union { unsigned int i; float f; } c;
    c.i = ((unsigned int)u) << 16;
    return c.f;
}

// ---------------- Kernel 1: Y precompute (537 MFLOP, no LDS/barriers) ----------
// grid = 4 * ceil(NPE/8); block = 256 (thread = output col o). 8 rows per block.
// pe loads are block-uniform -> scalar loads (1 fetch/block, SGPR broadcast).
__global__ __launch_bounds__(256) void precompute_Y(
        const float* __restrict__ pe,
        const float* __restrict__ W,
        const float* __restrict__ bias,
        __hip_bfloat16* __restrict__ Y,
        int NPE) {
    const int H = 256;
    const int ntile = (NPE + 7) >> 3;
    const int k  = blockIdx.x / ntile;
    const int r0 = (blockIdx.x % ntile) << 3;
    const int o  = threadIdx.x;
    const float* __restrict__ Wk = W + (size_t)k * H * H;

    int rows[8];
#pragma unroll
    for (int r = 0; r < 8; ++r) rows[r] = min(r0 + r, NPE - 1);

    f32x2 acc[8];
#pragma unroll
    for (int r = 0; r < 8; ++r) { acc[r].x = 0.f; acc[r].y = 0.f; }

#pragma unroll 2
    for (int h = 0; h < 256; h += 4) {
        f32x2 wa, wb;
        wa.x = Wk[(h + 0) * H + o];
        wa.y = Wk[(h + 1) * H + o];
        wb.x = Wk[(h + 2) * H + o];
        wb.y = Wk[(h + 3) * H + o];
#pragma unroll
        for (int r = 0; r < 8; ++r) {
            const f32x4 p = *reinterpret_cast<const f32x4*>(&pe[rows[r] * H + h]);
            f32x2 pa, pb;
            pa.x = p.x; pa.y = p.y;
            pb.x = p.z; pb.y = p.w;
            acc[r] += pa * wa + pb * wb;   // v_pk_fma_f32 candidates
        }
    }

    const float bv = (k == 0) ? bias[o] : 0.f;
#pragma unroll
    for (int r = 0; r < 8; ++r) {
        const int rr = r0 + r;
        if (rr < NPE)
            Y[((size_t)k * NPE + rr) * H + o] =
                __float2bfloat16(acc[r].x + acc[r].y + bv);
    }
}

// ---------------- Kernel 2: gather-add + leaky ReLU (write-bound) -------------
// H=256. Block=256 threads = 4 j's; 64 lanes per j. Each wave reads 4 table
// rows as full contiguous 512 B loads and writes one 1 KB contiguous NT store.
__global__ __launch_bounds__(256) void gather_add_bf16(
        const int* __restrict__ pos_s,
        const int* __restrict__ pos_e,
        const __hip_bfloat16* __restrict__ Y,
        float* __restrict__ out,
        int S, int ML, int NPE) {
    const int t  = threadIdx.x;
    const int jq = t >> 6;          // j within block (0..3)
    const int ln = t & 63;          // float4 lane within row
    const int S4 = S >> 2;

    const int blk = blockIdx.x;
    const int j   = ((blk % S4) << 2) + jq;
    const int i   = (blk / S4) % S;
    const int bb  = blk / (S4 * S);

    const int si = pos_s[bb * S + i];
    const int ei = pos_e[bb * S + i];
    const int sj = pos_s[bb * S + j];
    const int ej = pos_e[bb * S + j];

    const int r0 = 0 * NPE + si - sj + ML;
    const int r1 = 1 * NPE + si - ej + ML;
    const int r2 = 2 * NPE + ei - sj + ML;
    const int r3 = 3 * NPE + ei - ej + ML;

    const ushort4* __restrict__ Yv = reinterpret_cast<const ushort4*>(Y);
    ushort4 u0 = Yv[((size_t)r0 << 6) + ln];
    ushort4 u1 = Yv[((size_t)r1 << 6) + ln];
    ushort4 u2 = Yv[((size_t)r2 << 6) + ln];
    ushort4 u3 = Yv[((size_t)r3 << 6) + ln];

    f32x4 v;
    v.x = lrelu(bf2f(u0.x) + bf2f(u1.x) + bf2f(u2.x) + bf2f(u3.x));
    v.y = lrelu(bf2f(u0.y) + bf2f(u1.y) + bf2f(u2.y) + bf2f(u3.y));
    v.z = lrelu(bf2f(u0.z) + bf2f(u1.z) + bf2f(u2.z) + bf2f(u3.z));
    v.w = lrelu(bf2f(u0.w) + bf2f(u1.w) + bf2f(u2.w) + bf2f(u3.w));

    f32x4* __restrict__ op = reinterpret_cast<f32x4*>(out) +
                             ((((size_t)bb * S + i) * S + j) << 6) + ln;
    __builtin_nontemporal_store(v, op);
}

// ---------------- Fallback: direct compute (only if ws too small) -------------
__global__ void direct_kernel(const int* __restrict__ pos_s,
                              const int* __restrict__ pos_e,
                              const float* __restrict__ pe,
                              const float* __restrict__ W,
                              const float* __restrict__ bias,
                              float* __restrict__ out,
                              int B, int S, int H, int ML) {
    const int blk = blockIdx.x;
    const int j   = blk % S;
    const int i   = (blk / S) % S;
    const int bb  = blk / (S * S);
    const int o   = threadIdx.x;

    const int si = pos_s[bb * S + i];
    const int ei = pos_e[bb * S + i];
    const int sj = pos_s[bb * S + j];
    const int ej = pos_e[bb * S + j];

    const int rss = si - sj + ML;
    const int rse = si - ej + ML;
    const int res = ei - sj + ML;
    const int ree = ei - ej + ML;

    float acc = bias[o];
    for (int h = 0; h < H; ++h) {
        acc += pe[rss * H + h] * W[(0 * H + h) * H + o];
        acc += pe[rse * H + h] * W[(1 * H + h) * H + o];
        acc += pe[res * H + h] * W[(2 * H + h) * H + o];
        acc += pe[ree * H + h] * W[(3 * H + h) * H + o];
    }
    out[(((size_t)bb * S + i) * S + j) * H + o] = lrelu(acc);
}

extern "C" void kernel_launch(void* const* d_in, const int* in_sizes, int n_in,
                              void* d_out, int out_size, void* d_ws, size_t ws_size,
                              hipStream_t stream) {
    const int*   pos_s = (const int*)d_in[0];
    const int*   pos_e = (const int*)d_in[1];
    const float* pe    = (const float*)d_in[2];
    const float* W     = (const float*)d_in[3];
    const float* bias  = (const float*)d_in[4];
    float*       out   = (float*)d_out;

    const int H   = in_sizes[4];                 // 256
    const int NPE = in_sizes[2] / H;             // 1025
    const int ML  = (NPE - 1) / 2;               // 512
    const int BS  = in_sizes[0];                 // B*S
    const int S   = (int)((long long)out_size / ((long long)BS * H)); // 256
    const int B   = BS / S;                      // 2

    const size_t need = (size_t)4 * NPE * H * sizeof(__hip_bfloat16);  // 2.1 MB

    if (ws_size >= need && H == 256 && (S & 3) == 0) {
        __hip_bfloat16* Y = (__hip_bfloat16*)d_ws;
        const int ntile = (NPE + 7) >> 3;
        precompute_Y<<<4 * ntile, 256, 0, stream>>>(pe, W, bias, Y, NPE);
        const int nblk = B * S * (S >> 2);
        gather_add_bf16<<<nblk, 256, 0, stream>>>(pos_s, pos_e, Y, out, S, ML, NPE);
    } else {
        direct_kernel<<<B * S * S, H, 0, stream>>>(pos_s, pos_e, pe, W, bias, out,
                                                   B, S, H, ML);
    }
}